// Round 1
// baseline (10888.227 us; speedup 1.0000x reference)
//
#include <hip/hip_runtime.h>
#include <math.h>

#define D 256
#define NH 4
#define HDIM 64
#define FFD 2048
#define NL 3
#define VOC 30000
#define BPTT 20
#define BATCH 64
#define NMAX (BPTT*BATCH)   /* 1280 */

// ---------------- mask from target_ingrs ----------------
__global__ void k_mask(const int* __restrict__ ids, int* __restrict__ mask) {
  int b = threadIdx.x;
  int run = 1;
  for (int j = 0; j < BPTT; ++j) {
    if (j > 0 && ids[b*BPTT + j] == 2) run = 0;
    mask[b*BPTT + j] = run;
  }
}

// ---------------- img_embed = image_feats @ W_g2e + b_g2e -> embeds row 0 ----------------
__global__ __launch_bounds__(256) void k_img(const float* __restrict__ feats,
                                             const float* __restrict__ Wg,
                                             const float* __restrict__ bg,
                                             float* __restrict__ embeds) {
  __shared__ float xs[2048];
  int b = blockIdx.x, tid = threadIdx.x;
  for (int j = 0; j < 8; ++j) xs[tid + j*256] = feats[b*2048 + tid + j*256];
  __syncthreads();
  float acc = 0.f;
  for (int k = 0; k < 2048; k += 4) {
    float4 xv = *(const float4*)&xs[k];
    acc += xv.x * Wg[(k+0)*D + tid];
    acc += xv.y * Wg[(k+1)*D + tid];
    acc += xv.z * Wg[(k+2)*D + tid];
    acc += xv.w * Wg[(k+3)*D + tid];
  }
  embeds[b*D + tid] = acc + bg[tid];  // token s=0,b -> row b
}

// ---------------- generic GEMM: C[N,M] = A[N,lda-sliced] @ W[K,M] (+bias)(+relu) ----------------
// tile: 8 tokens x 256 cols, 256 threads, acc[2][4] per thread.
// grid.z = k-split chunks: chunk z covers k in [z*klen, (z+1)*klen), writes C + z*pstride.
__global__ __launch_bounds__(256) void k_gemm8(
    const float* __restrict__ A, int lda,
    const float* __restrict__ W,
    const float* __restrict__ bias,
    float* __restrict__ C, long pstride,
    int klen, int M, int relu)
{
  __shared__ float As[8][256];
  const int tid  = threadIdx.x;
  const int tok0 = blockIdx.x * 8;
  const int colb = blockIdx.y * 256;
  const int z    = blockIdx.z;
  const int kbeg = z * klen;
  C += (long)z * pstride;
  const int colg = tid & 63;   // 64 col groups of 4
  const int tokg = tid >> 6;   // 4 token groups of 2
  const int col  = colb + colg*4;
  int colL = col;
  if (colL > M-4) colL = M-4;  // clamp loads; stores guarded by col<M

  float acc[2][4] = {{0.f,0.f,0.f,0.f},{0.f,0.f,0.f,0.f}};

  for (int k0 = 0; k0 < klen; k0 += 256) {
    __syncthreads();
#pragma unroll
    for (int j = 0; j < 8; ++j)
      As[j][tid] = A[(long)(tok0 + j)*lda + kbeg + k0 + tid];
    __syncthreads();
    const float* Wp = W + (long)(kbeg + k0)*M + colL;
#pragma unroll 2
    for (int kk = 0; kk < 256; kk += 4) {
      float a[2][4], w[4][4];
      *(float4*)a[0] = *(const float4*)&As[tokg*2+0][kk];
      *(float4*)a[1] = *(const float4*)&As[tokg*2+1][kk];
      *(float4*)w[0] = *(const float4*)(Wp + (long)(kk+0)*M);
      *(float4*)w[1] = *(const float4*)(Wp + (long)(kk+1)*M);
      *(float4*)w[2] = *(const float4*)(Wp + (long)(kk+2)*M);
      *(float4*)w[3] = *(const float4*)(Wp + (long)(kk+3)*M);
#pragma unroll
      for (int j = 0; j < 2; ++j)
#pragma unroll
        for (int c = 0; c < 4; ++c)
#pragma unroll
          for (int q = 0; q < 4; ++q)
            acc[j][c] += a[j][q] * w[q][c];
    }
  }

  if (col < M) {
    float bv[4] = {0.f,0.f,0.f,0.f};
    if (bias) *(float4*)bv = *(const float4*)(bias + col);
#pragma unroll
    for (int j = 0; j < 2; ++j) {
      float v[4];
#pragma unroll
      for (int c = 0; c < 4; ++c) {
        v[c] = acc[j][c] + bv[c];
        if (relu) v[c] = fmaxf(v[c], 0.f);
      }
      *(float4*)(C + (long)(tok0 + tokg*2 + j)*M + col) = *(float4*)v;
    }
  }
}

// ---------------- residual + bias + sum(parts) -> LayerNorm ----------------
__global__ __launch_bounds__(256) void k_resln(
    const float* __restrict__ x, const float* __restrict__ parts, int nparts, long pstride,
    const float* __restrict__ bias, const float* __restrict__ g, const float* __restrict__ be,
    float* __restrict__ out)
{
  __shared__ float red[4];
  int tok = blockIdx.x, tid = threadIdx.x;
  float v = x[(long)tok*D + tid] + bias[tid];
  for (int p = 0; p < nparts; ++p) v += parts[(long)p*pstride + (long)tok*D + tid];

  float s = v;
  for (int off = 32; off; off >>= 1) s += __shfl_down(s, off);
  if ((tid & 63) == 0) red[tid >> 6] = s;
  __syncthreads();
  float mu = (red[0]+red[1]+red[2]+red[3]) * (1.0f/D);
  __syncthreads();
  float dv = v - mu;
  float q = dv*dv;
  for (int off = 32; off; off >>= 1) q += __shfl_down(q, off);
  if ((tid & 63) == 0) red[tid >> 6] = q;
  __syncthreads();
  float var = (red[0]+red[1]+red[2]+red[3]) * (1.0f/D);
  float inv = 1.0f / sqrtf(var + 1e-5f);
  out[(long)tok*D + tid] = dv * inv * g[tid] + be[tid];
}

// ---------------- attention for one (b,h): scores->softmax->PV ----------------
__global__ __launch_bounds__(64) void k_attn(const float* __restrict__ qkv,
                                             float* __restrict__ o, int S)
{
  __shared__ float qs[BPTT*HDIM], ks[BPTT*HDIM], vs[BPTT*HDIM], ps[BPTT*(BPTT+1)];
  int bh = blockIdx.x;
  int b = bh & 63, h = bh >> 6;
  int d = threadIdx.x;
  for (int s = 0; s < S; ++s) {
    long base = (long)(s*BATCH + b)*(3*D) + h*HDIM + d;
    qs[s*HDIM+d] = qkv[base];
    ks[s*HDIM+d] = qkv[base + D];
    vs[s*HDIM+d] = qkv[base + 2*D];
  }
  __syncthreads();
  for (int p = d; p < S*S; p += 64) {
    int si = p / S, ti = p - si*S;
    float acc = 0.f;
#pragma unroll 4
    for (int k = 0; k < HDIM; ++k) acc += qs[si*HDIM+k] * ks[ti*HDIM+k];
    ps[si*(BPTT+1)+ti] = acc * 0.125f;  // 1/sqrt(64)
  }
  __syncthreads();
  if (d < S) {
    float m = -1e30f;
    for (int t = 0; t < S; ++t) m = fmaxf(m, ps[d*(BPTT+1)+t]);
    float sum = 0.f;
    for (int t = 0; t < S; ++t) { float e = expf(ps[d*(BPTT+1)+t] - m); ps[d*(BPTT+1)+t] = e; sum += e; }
    float inv = 1.0f / sum;
    for (int t = 0; t < S; ++t) ps[d*(BPTT+1)+t] *= inv;
  }
  __syncthreads();
  for (int s = 0; s < S; ++s) {
    float acc = 0.f;
    for (int t = 0; t < S; ++t) acc += ps[s*(BPTT+1)+t] * vs[t*HDIM+d];
    o[(long)(s*BATCH+b)*D + h*HDIM + d] = acc;
  }
}

// ---------------- vocab softmax + argmax + outputs + next-embed ----------------
__global__ __launch_bounds__(256) void k_vocab(
    const float* __restrict__ logits, const int* __restrict__ mask,
    float* __restrict__ out_probs, float* __restrict__ out_words, float* __restrict__ out_eos,
    const float* __restrict__ emb, float* __restrict__ embeds, int step)
{
  __shared__ float redA[4];
  __shared__ float r_s[4];
  __shared__ float r_em[4];
  __shared__ int   r_ei[4];
  int b = blockIdx.x, tid = threadIdx.x;
  const float* lrow = logits + (long)b*VOC;

  // pass 1: global max of logits (for stable softmax, matching jax)
  float m = -1e30f;
  for (int c = tid; c < VOC; c += 256) m = fmaxf(m, lrow[c]);
  for (int off = 32; off; off >>= 1) m = fmaxf(m, __shfl_down(m, off));
  if ((tid & 63) == 0) redA[tid >> 6] = m;
  __syncthreads();
  float gmax = fmaxf(fmaxf(redA[0],redA[1]), fmaxf(redA[2],redA[3]));
  __syncthreads();

  // pass 2: sum of exp, and argmax of exp (tie -> smallest index, like np/jnp first-occurrence)
  float s = 0.f, em = -1.0f;
  int ei = VOC;
  for (int c = tid; c < VOC; c += 256) {
    float e = expf(lrow[c] - gmax);
    s += e;
    if (e > em) { em = e; ei = c; }
  }
  for (int off = 32; off; off >>= 1) {
    float em2 = __shfl_down(em, off);
    int   ei2 = __shfl_down(ei, off);
    if (em2 > em || (em2 == em && ei2 < ei)) { em = em2; ei = ei2; }
    s += __shfl_down(s, off);
  }
  if ((tid & 63) == 0) { r_s[tid>>6] = s; r_em[tid>>6] = em; r_ei[tid>>6] = ei; }
  __syncthreads();
  float Ssum = r_s[0]+r_s[1]+r_s[2]+r_s[3];
  em = r_em[0]; ei = r_ei[0];
  for (int w = 1; w < 4; ++w)
    if (r_em[w] > em || (r_em[w] == em && r_ei[w] < ei)) { em = r_em[w]; ei = r_ei[w]; }

  int mk = mask[b*BPTT + step];

  // pass 3: probs -> running max into d_out; eos; word
  for (int c = tid; c < VOC; c += 256) {
    float p = expf(lrow[c] - gmax) / Ssum;
    float* op = out_probs + (long)b*VOC + c;
    if (step == 0) *op = p;               // mask[:,0] is always 1
    else if (mk)   *op = fmaxf(*op, p);
    if (c == 2) out_eos[b*BPTT + step] = p;
  }
  if (tid == 0) out_words[b*BPTT + step] = mk ? (float)ei : 0.0f;
  if (step + 1 < BPTT)
    embeds[(long)((step+1)*BATCH + b)*D + tid] = emb[(long)ei*D + tid];
}

// ---------------- host ----------------
extern "C" void kernel_launch(void* const* d_in, const int* in_sizes, int n_in,
                              void* d_out, int out_size, void* d_ws, size_t ws_size,
                              hipStream_t stream) {
  const float* image_feats = (const float*)d_in[0];
  const int*   target      = (const int*)  d_in[1];
  const float* emb_table   = (const float*)d_in[2];
  const float* W_g2e       = (const float*)d_in[3];
  const float* b_g2e       = (const float*)d_in[4];
  const float* W_out       = (const float*)d_in[5];
  const float* b_out       = (const float*)d_in[6];
  const float* Wqkv        = (const float*)d_in[7];
  const float* bqkv        = (const float*)d_in[8];
  const float* Wo          = (const float*)d_in[9];
  const float* bo          = (const float*)d_in[10];
  const float* W1          = (const float*)d_in[11];
  const float* b1          = (const float*)d_in[12];
  const float* W2          = (const float*)d_in[13];
  const float* b2          = (const float*)d_in[14];
  const float* g1          = (const float*)d_in[15];
  const float* be1         = (const float*)d_in[16];
  const float* g2          = (const float*)d_in[17];
  const float* be2         = (const float*)d_in[18];

  float* out_probs = (float*)d_out;                       // 64*30000
  float* out_words = out_probs + (long)BATCH*VOC;         // 64*20
  float* out_eos   = out_words + BATCH*BPTT;              // 64*20

  char* ws = (char*)d_ws;
  float* embeds = (float*)ws;  ws += sizeof(float)*(long)NMAX*D;
  float* xbuf   = (float*)ws;  ws += sizeof(float)*(long)NMAX*D;
  float* qkvb   = (float*)ws;  ws += sizeof(float)*(long)NMAX*3*D;
  float* obuf   = (float*)ws;  ws += sizeof(float)*(long)NMAX*D;
  float* pbuf   = (float*)ws;  ws += sizeof(float)*(long)4*NMAX*D;
  float* ffb    = (float*)ws;  ws += sizeof(float)*(long)NMAX*FFD;
  float* logits = (float*)ws;  ws += sizeof(float)*(long)BATCH*VOC;
  int*   maskb  = (int*)ws;    ws += sizeof(int)*BATCH*BPTT;

  k_mask<<<1, 64, 0, stream>>>(target, maskb);
  k_img<<<64, 256, 0, stream>>>(image_feats, W_g2e, b_g2e, embeds);

  for (int i = 0; i < BPTT; ++i) {
    int N = (i+1)*BATCH;
    for (int l = 0; l < NL; ++l) {
      const float* X = (l == 0) ? embeds : xbuf;
      // qkv = X @ Wqkv[l] + bqkv[l]
      k_gemm8<<<dim3(N/8, 3, 1), 256, 0, stream>>>(X, D, Wqkv + (long)l*D*3*D, bqkv + (long)l*3*D,
                                                   qkvb, 0, D, 3*D, 0);
      // attention
      k_attn<<<dim3(BATCH*NH), 64, 0, stream>>>(qkvb, obuf, i+1);
      // proj = o @ Wo[l]   (bias folded into resln)
      k_gemm8<<<dim3(N/8, 1, 1), 256, 0, stream>>>(obuf, D, Wo + (long)l*D*D, nullptr,
                                                   pbuf, 0, D, D, 0);
      // x = LN(X + proj + bo)
      k_resln<<<dim3(N), 256, 0, stream>>>(X, pbuf, 1, 0, bo + (long)l*D, g1 + (long)l*D, be1 + (long)l*D, xbuf);
      // ff = relu(x @ W1[l] + b1[l])
      k_gemm8<<<dim3(N/8, FFD/256, 1), 256, 0, stream>>>(xbuf, D, W1 + (long)l*D*FFD, b1 + (long)l*FFD,
                                                         ffb, 0, D, FFD, 1);
      // ff @ W2[l] split-K into 4 partials
      k_gemm8<<<dim3(N/8, 1, 4), 256, 0, stream>>>(ffb, FFD, W2 + (long)l*FFD*D, nullptr,
                                                   pbuf, (long)NMAX*D, FFD/4, D, 0);
      // x = LN(x + sum(partials) + b2)
      k_resln<<<dim3(N), 256, 0, stream>>>(xbuf, pbuf, 4, (long)NMAX*D, b2 + (long)l*D, g2 + (long)l*D, be2 + (long)l*D, xbuf);
    }
    // logits for last-token rows
    k_gemm8<<<dim3(BATCH/8, (VOC+255)/256, 1), 256, 0, stream>>>(xbuf + (long)i*BATCH*D, D, W_out, b_out,
                                                                 logits, 0, D, VOC, 0);
    // softmax + argmax + outputs + next embedding
    k_vocab<<<dim3(BATCH), 256, 0, stream>>>(logits, maskb, out_probs, out_words, out_eos,
                                             emb_table, embeds, i);
  }
}